// Round 11
// baseline (200.750 us; speedup 1.0000x reference)
//
#include <hip/hip_runtime.h>

typedef __bf16 bf16x8 __attribute__((ext_vector_type(8)));
typedef float f32x4 __attribute__((ext_vector_type(4)));

constexpr int Bsz = 16;
constexpr int Nsz = 1024;
constexpr int Dsz = 256;
constexpr int Hsz = 4;
constexpr int HFsz = 256;
constexpr int BN = Bsz * Nsz;
constexpr float LOG2E = 1.44269504088896340736f;

__device__ __forceinline__ unsigned f2bf(float f) {   // RNE fp32->bf16 (finite in)
    unsigned u = __float_as_uint(f);
    return (u + 0x7FFFu + ((u >> 16) & 1u)) >> 16;
}

// ---------------------------------------------------------------------------
// Kernel 0: WbT[c][d] = bf16(W[d][c])  (transpose-convert, 256x256)
// ---------------------------------------------------------------------------
__global__ __launch_bounds__(256) void wcvt(const float* __restrict__ Wm,
                                            unsigned short* __restrict__ WbT) {
    const int t = threadIdx.x;
    const int c = blockIdx.x * 4 + (t >> 6);
    const int d0 = (t & 63) * 4;
    const float v0 = Wm[(size_t)(d0 + 0) * HFsz + c];
    const float v1 = Wm[(size_t)(d0 + 1) * HFsz + c];
    const float v2 = Wm[(size_t)(d0 + 2) * HFsz + c];
    const float v3 = Wm[(size_t)(d0 + 3) * HFsz + c];
    uint2 pk;
    pk.x = f2bf(v0) | (f2bf(v1) << 16);
    pk.y = f2bf(v2) | (f2bf(v3) << 16);
    *(uint2*)&WbT[(size_t)c * Dsz + d0] = pk;   // coalesced 512B/wave
}

// ---------------------------------------------------------------------------
// Kernel 0.5: adj -> bitmask, tile-major layout.
// adjM byte address: (r>>4)*2048 + (j8>>3)*128 + (r&15)*8 + (j8&7)
//   where r = b*1024+i, j8 = j>>3, bit w of byte = (adj[r][j8*8+w] > 0.5).
// => for a 16-row i-tile and 64-col j-tile, the 16 uint64 row-masks are
//    CONTIGUOUS 128 B at ((b*64+it)*16 + jt)*128 -> one s_load burst in attn.
// ---------------------------------------------------------------------------
__global__ __launch_bounds__(256) void adjbin(const float* __restrict__ adj,
                                              unsigned char* __restrict__ adjM) {
    const int wg = (blockIdx.x * 256 + threadIdx.x) >> 6;   // wave id [0,2048)
    const int lane = threadIdx.x & 63;
#pragma unroll 1
    for (int s = wg; s < 32768; s += 2048) {                // 2 spans x 16384 rows
        const int r = s >> 1, c0 = (s & 1) * 512;
        const float4* src = (const float4*)(adj + (size_t)r * 1024 + c0 + lane * 8);
        const float4 a0 = src[0], a1 = src[1];              // 2 KB/wave, coalesced
        unsigned by = 0;
        by |= (a0.x > 0.5f) ? 1u : 0u;
        by |= (a0.y > 0.5f) ? 2u : 0u;
        by |= (a0.z > 0.5f) ? 4u : 0u;
        by |= (a0.w > 0.5f) ? 8u : 0u;
        by |= (a1.x > 0.5f) ? 16u : 0u;
        by |= (a1.y > 0.5f) ? 32u : 0u;
        by |= (a1.z > 0.5f) ? 64u : 0u;
        by |= (a1.w > 0.5f) ? 128u : 0u;
        const int j8 = (s & 1) * 64 + lane;
        adjM[(size_t)(r >> 4) * 2048 + (j8 >> 3) * 128 + (r & 15) * 8 + (j8 & 7)] =
            (unsigned char)by;
    }
}

// ---------------------------------------------------------------------------
// Kernel 1: hT = bf16(x @ W)^T via MFMA + fused e_src/e_dst (fp32 dots).
// e_src/e_dst stored PRE-SCALED by log2(e). (unchanged, verified)
// ---------------------------------------------------------------------------
__global__ __launch_bounds__(256) void gat_h_e3(
    const float* __restrict__ x,              // [BN][D]
    const unsigned short* __restrict__ WbT,   // [HF][D] bf16
    const float* __restrict__ a_src,          // [HF]
    const float* __restrict__ a_dst,          // [HF]
    unsigned short* __restrict__ hT,          // [B][HF][N] bf16
    float* __restrict__ esrcT,                // [B][H][N]  (x log2e)
    float* __restrict__ edstT)                // [B][H][N]  (x log2e)
{
    const int n0g = blockIdx.x * 32, b = n0g >> 10, n0 = n0g & 1023;
    const int t = threadIdx.x, lane = t & 63, w = t >> 6;
    const int m = lane & 15, q = lane >> 4;

    __shared__ alignas(16) unsigned short Lds[4 * 64 * 40];  // 10240 hw = 20 KB

    const float4* x4 = (const float4*)(x + (size_t)n0g * Dsz);
#pragma unroll
    for (int i = 0; i < 8; ++i) {
        const int f = t + 256 * i;
        const int row = f >> 6, d4 = (f & 63) * 4;
        const float4 xv = x4[f];
        uint2 pk;
        pk.x = f2bf(xv.x) | (f2bf(xv.y) << 16);
        pk.y = f2bf(xv.z) | (f2bf(xv.w) << 16);
        *(uint2*)&Lds[row * 264 + d4] = pk;
    }
    __syncthreads();

    const unsigned short* Ab = WbT + (size_t)(w * 64 + m) * Dsz + q * 8;
    f32x4 acc[4][2];
#pragma unroll
    for (int ht = 0; ht < 4; ++ht)
#pragma unroll
        for (int nt = 0; nt < 2; ++nt) acc[ht][nt] = (f32x4){0.f, 0.f, 0.f, 0.f};

#pragma unroll
    for (int kk = 0; kk < 8; ++kk) {
        const int k0 = kk * 32;
        const bf16x8 bfr0 = *(const bf16x8*)&Lds[(0 * 16 + m) * 264 + k0 + q * 8];
        const bf16x8 bfr1 = *(const bf16x8*)&Lds[(1 * 16 + m) * 264 + k0 + q * 8];
#pragma unroll
        for (int ht = 0; ht < 4; ++ht) {
            const bf16x8 afr = *(const bf16x8*)&Ab[ht * 16 * Dsz + k0];
            acc[ht][0] = __builtin_amdgcn_mfma_f32_16x16x32_bf16(afr, bfr0, acc[ht][0], 0, 0, 0);
            acc[ht][1] = __builtin_amdgcn_mfma_f32_16x16x32_bf16(afr, bfr1, acc[ht][1], 0, 0, 0);
        }
    }

    float ps0 = 0.f, ps1 = 0.f, pd0 = 0.f, pd1 = 0.f;
#pragma unroll
    for (int ht = 0; ht < 4; ++ht)
#pragma unroll
        for (int r = 0; r < 4; ++r) {
            const float as = a_src[w * 64 + ht * 16 + q * 4 + r];
            const float ad = a_dst[w * 64 + ht * 16 + q * 4 + r];
            ps0 += acc[ht][0][r] * as;  ps1 += acc[ht][1][r] * as;
            pd0 += acc[ht][0][r] * ad;  pd1 += acc[ht][1][r] * ad;
        }
    ps0 += __shfl_xor(ps0, 16, 64); ps0 += __shfl_xor(ps0, 32, 64);
    ps1 += __shfl_xor(ps1, 16, 64); ps1 += __shfl_xor(ps1, 32, 64);
    pd0 += __shfl_xor(pd0, 16, 64); pd0 += __shfl_xor(pd0, 32, 64);
    pd1 += __shfl_xor(pd1, 16, 64); pd1 += __shfl_xor(pd1, 32, 64);
    if (q == 0) {
        const size_t eb = (size_t)(b * Hsz + w) * Nsz + n0;
        esrcT[eb + m]      = ps0 * LOG2E;  esrcT[eb + 16 + m] = ps1 * LOG2E;
        edstT[eb + m]      = pd0 * LOG2E;  edstT[eb + 16 + m] = pd1 * LOG2E;
    }

    __syncthreads();   // xs no longer needed; reuse LDS as hs[4][64][40]

#pragma unroll
    for (int ht = 0; ht < 4; ++ht)
#pragma unroll
        for (int r = 0; r < 4; ++r) {
            const int hf = ht * 16 + q * 4 + r;
            Lds[w * 2560 + hf * 40 + m]      = (unsigned short)f2bf(acc[ht][0][r]);
            Lds[w * 2560 + hf * 40 + 16 + m] = (unsigned short)f2bf(acc[ht][1][r]);
        }
#pragma unroll
    for (int s = 0; s < 4; ++s) {
        const int hf = s * 16 + (lane >> 2), ck = lane & 3;
        const bf16x8 hv = *(const bf16x8*)&Lds[w * 2560 + hf * 40 + ck * 8];
        *(bf16x8*)&hT[(size_t)(b * HFsz + w * 64 + hf) * Nsz + n0 + ck * 8] = hv;
    }
}

// ---------------------------------------------------------------------------
// Kernel 2 (v10): v8 + FULL one-tile-ahead register pipeline.
// R10 post-mortem: (128,8) was neutral -- occupancy stuck ~78%, dur 67us,
// VALU 20%. Occupancy is not the lever; the per-tile serial chain is. v8
// exposes 3 latencies per tile: bfr L2 loads (~300cy), mask s_loads (~200cy),
// Pw ds round-trip (~120cy); only es was prefetched. v10 double-buffers ALL
// of them one full tile ahead: bfr in 64 VGPRs (2x8 bf16x8), masks in 2x16
// u64 SGPRs (s-constraint keeps cndmask selectors scalar), es ping-pong as
// before. Every operand consumed at tile t was issued at t-1 (~110 VALU +
// 10 MFMA earlier); compiler's counted vmcnt/lgkmcnt keeps them in flight.
// Cost: launch_bounds(128,4) (128-reg cap, est ~110) -> 16 waves/CU = two
// full generations of 8 blocks/CU, no tail. v4 proved 16 deep-prefetched
// waves beat 25 starved ones.
// ---------------------------------------------------------------------------
__global__ __launch_bounds__(128, 4) void gat_attn10(
    const unsigned char* __restrict__ adjM, // [B][64][16][128B] bit-tiles
    const unsigned short* __restrict__ hT,  // [B][HF][N] bf16
    const float* __restrict__ esrcT,        // [B][H][N] (x log2e)
    const float* __restrict__ edstT,        // [B][H][N] (x log2e)
    const float* __restrict__ bias,         // [HF]
    float* __restrict__ outp)               // [BN][HF]
{
    const int gid = blockIdx.x;
    const int b  = gid & 15;                 // xcd = gid%8 -> b%8 (L2 locality)
    const int hw = (gid >> 4) & 3;           // head
    const int it = gid >> 6, i0 = it * 16;
    const int t = threadIdx.x;
    const int lane = t & 63, jh = t >> 6;    // jh = j-half (2 waves)
    const int m = lane & 15, q = lane >> 4;

    // [0,4608): 2 wave-private P tiles [16][72] ushort (main loop);
    // epilogue aliases all 10240 B as comb[2][64][20] f32.
    __shared__ alignas(16) float smem[2560];
    unsigned short* Pw = (unsigned short*)smem + jh * 1152;

    const float* esb = esrcT + (size_t)(b * Hsz + hw) * Nsz;
    const float* edb = edstT + (size_t)(b * Hsz + hw) * Nsz + i0;
    const unsigned short* hTb = hT + (size_t)(b * HFsz + hw * 64 + m) * Nsz + q * 8;
    const unsigned long long* mkb =
        (const unsigned long long*)(adjM + (size_t)(b * 64 + it) * 2048);

    // ed for the 16 rows: wave-uniform -> SGPRs
    float edv[16];
#pragma unroll
    for (int il = 0; il < 16; ++il)
        edv[il] = __uint_as_float(
            __builtin_amdgcn_readfirstlane(__float_as_uint(edb[il])));

    bf16x8 ones;                             // denominator row-sum B-frag
#pragma unroll
    for (int i = 0; i < 8; ++i)
        ((unsigned short*)&ones)[i] = 0x3F80;   // bf16 1.0

    f32x4 acc[4];
#pragma unroll
    for (int nt = 0; nt < 4; ++nt) acc[nt] = (f32x4){0.f, 0.f, 0.f, 0.f};
    f32x4 acc5 = (f32x4){0.f, 0.f, 0.f, 0.f};

    const int jt0 = __builtin_amdgcn_readfirstlane(jh * 8);  // first j-tile

    // ---- prologue: fill buffer A for tile jt0 ----
    unsigned long long mkA[16], mkB[16];
    bf16x8 bfA[8], bfB[8];
    float esA, esB;
#pragma unroll
    for (int il = 0; il < 16; ++il) mkA[il] = mkb[jt0 * 16 + il];
#pragma unroll
    for (int nt = 0; nt < 4; ++nt) {
        bfA[nt]     = *(const bf16x8*)&hTb[(size_t)nt * 16 * Nsz + jt0 * 64];
        bfA[4 + nt] = *(const bf16x8*)&hTb[(size_t)nt * 16 * Nsz + jt0 * 64 + 32];
    }
    esA = esb[jt0 * 64 + lane];

    auto body = [&](int jl, unsigned long long (&mkC)[16], bf16x8 (&bfC)[8],
                    float& esC, unsigned long long (&mkN)[16], bf16x8 (&bfN)[8],
                    float& esN) {
        // (1) prefetch EVERYTHING for tile t+1 (dummy reload of t on last)
        const int jnx = (jl < 7) ? (jt0 + jl + 1) : (jt0 + jl);
        const int jnu = __builtin_amdgcn_readfirstlane(jnx);
#pragma unroll
        for (int nt = 0; nt < 4; ++nt) {
            bfN[nt]     = *(const bf16x8*)&hTb[(size_t)nt * 16 * Nsz + jnx * 64];
            bfN[4 + nt] = *(const bf16x8*)&hTb[(size_t)nt * 16 * Nsz + jnx * 64 + 32];
        }
        esN = esb[jnx * 64 + lane];
#pragma unroll
        for (int il = 0; il < 16; ++il) mkN[il] = mkb[jnu * 16 + il];

        // (2) exp chain for tile t: only registers (edv, esC, mkC)
#pragma unroll
        for (int il = 0; il < 16; ++il) {
            float v = edv[il] + esC;          // already x log2e
            v = fmaxf(v, 0.2f * v);           // LeakyReLU (scale>0 commutes)
            float p;
            asm("v_exp_f32 %0, %1" : "=v"(p) : "v"(v));        // 2^v
            unsigned ru;                      // bit lane of mkC selects p or 0
            asm("v_cndmask_b32 %0, 0, %1, %2"
                : "=v"(ru) : "v"(p), "s"(mkC[il]));
            Pw[il * 72 + lane] = (unsigned short)(ru >> 16);
        }

        // (3) MFMAs for tile t: bfC was loaded LAST tile -> no VMEM wait
        {
            const bf16x8 af0 = *(const bf16x8*)&Pw[m * 72 + q * 8];
#pragma unroll
            for (int nt = 0; nt < 4; ++nt)
                acc[nt] = __builtin_amdgcn_mfma_f32_16x16x32_bf16(
                    af0, bfC[nt], acc[nt], 0, 0, 0);
            acc5 = __builtin_amdgcn_mfma_f32_16x16x32_bf16(af0, ones, acc5, 0, 0, 0);
        }
        {
            const bf16x8 af1 = *(const bf16x8*)&Pw[m * 72 + 32 + q * 8];
#pragma unroll
            for (int nt = 0; nt < 4; ++nt)
                acc[nt] = __builtin_amdgcn_mfma_f32_16x16x32_bf16(
                    af1, bfC[4 + nt], acc[nt], 0, 0, 0);
            acc5 = __builtin_amdgcn_mfma_f32_16x16x32_bf16(af1, ones, acc5, 0, 0, 0);
        }
    };

#pragma unroll 1
    for (int jp = 0; jp < 8; jp += 2) {      // ping-pong: no register rotates
        body(jp,     mkA, bfA, esA, mkB, bfB, esB);
        body(jp + 1, mkB, bfB, esB, mkA, bfA, esA);
    }

    // ---- combine the 2 j-half partials (verified v5 mapping, j2 over 2) ----
    __syncthreads();                         // only barrier before epilogue
    {
        float* cw = smem + t * 20;           // (jh*64+lane)*20 == t*20
#pragma unroll
        for (int nt = 0; nt < 4; ++nt)
#pragma unroll
            for (int r = 0; r < 4; ++r) cw[nt * 4 + r] = acc[nt][r];
#pragma unroll
        for (int r = 0; r < 4; ++r) cw[16 + r] = acc5[r];   // den rows q*4+r
    }
    __syncthreads();

#pragma unroll
    for (int u = 0; u < 2; ++u) {
        const int idx = t * 2 + u;               // 256 float4 cells (16x16)
        const int row = idx >> 4, c4 = idx & 15;
        const int rq = row >> 2, rr = row & 3;
        const int nt4 = (c4 >> 2) * 4, mb = (c4 & 3) * 4;
        float n0 = 0.f, n1 = 0.f, n2 = 0.f, n3 = 0.f, den = 0.f;
#pragma unroll
        for (int j2 = 0; j2 < 2; ++j2) {
            const float* cb = smem + (j2 * 64 + rq * 16) * 20;
            den += cb[16 + rr];                  // m=0 copy
            n0 += cb[(mb + 0) * 20 + nt4 + rr];
            n1 += cb[(mb + 1) * 20 + nt4 + rr];
            n2 += cb[(mb + 2) * 20 + nt4 + rr];
            n3 += cb[(mb + 3) * 20 + nt4 + rr];
        }
        const float inv = 1.f / den;
        const float4 b4 = *(const float4*)&bias[hw * 64 + c4 * 4];
        float4 o;
        o.x = n0 * inv + b4.x;  o.y = n1 * inv + b4.y;
        o.z = n2 * inv + b4.z;  o.w = n3 * inv + b4.w;
        *(float4*)&outp[(size_t)(b * Nsz + i0 + row) * HFsz + hw * 64 + c4 * 4] = o;
    }
}

// ---------------------------------------------------------------------------
extern "C" void kernel_launch(void* const* d_in, const int* in_sizes, int n_in,
                              void* d_out, int out_size, void* d_ws, size_t ws_size,
                              hipStream_t stream) {
    const float* x     = (const float*)d_in[0];
    const float* adj   = (const float*)d_in[1];
    const float* Wm    = (const float*)d_in[2];
    const float* a_src = (const float*)d_in[3];
    const float* a_dst = (const float*)d_in[4];
    const float* bias  = (const float*)d_in[5];
    float* outp = (float*)d_out;

    // ws: hT bf16 (8MB) | WbT bf16 (128KB) | esrcT (256KB) | edstT (256KB) | adjM (2MB)
    unsigned short* hT  = (unsigned short*)d_ws;
    unsigned short* WbT = hT + (size_t)BN * HFsz;
    float* esrcT = (float*)(WbT + (size_t)HFsz * Dsz);
    float* edstT = esrcT + (size_t)Bsz * Hsz * Nsz;
    unsigned char* adjM = (unsigned char*)(edstT + (size_t)Bsz * Hsz * Nsz);

    adjbin<<<dim3(512), dim3(256), 0, stream>>>(adj, adjM);
    wcvt<<<dim3(64), dim3(256), 0, stream>>>(Wm, WbT);
    gat_h_e3<<<dim3(BN / 32), dim3(256), 0, stream>>>(x, WbT, a_src, a_dst,
                                                      hT, esrcT, edstT);
    gat_attn10<<<dim3(4096), dim3(128), 0, stream>>>(adjM, hT, esrcT, edstT,
                                                     bias, outp);
}

// Round 12
// 199.102 us; speedup vs baseline: 1.0083x; 1.0083x over previous
//
#include <hip/hip_runtime.h>

typedef __bf16 bf16x8 __attribute__((ext_vector_type(8)));
typedef float f32x4 __attribute__((ext_vector_type(4)));

constexpr int Bsz = 16;
constexpr int Nsz = 1024;
constexpr int Dsz = 256;
constexpr int Hsz = 4;
constexpr int HFsz = 256;
constexpr int BN = Bsz * Nsz;
constexpr float LOG2E = 1.44269504088896340736f;

__device__ __forceinline__ unsigned f2bf(float f) {   // RNE fp32->bf16 (finite in)
    unsigned u = __float_as_uint(f);
    return (u + 0x7FFFu + ((u >> 16) & 1u)) >> 16;
}

// ---------------------------------------------------------------------------
// Kernel 0: WbT[c][d] = bf16(W[d][c])  (transpose-convert, 256x256)
// ---------------------------------------------------------------------------
__global__ __launch_bounds__(256) void wcvt(const float* __restrict__ Wm,
                                            unsigned short* __restrict__ WbT) {
    const int t = threadIdx.x;
    const int c = blockIdx.x * 4 + (t >> 6);
    const int d0 = (t & 63) * 4;
    const float v0 = Wm[(size_t)(d0 + 0) * HFsz + c];
    const float v1 = Wm[(size_t)(d0 + 1) * HFsz + c];
    const float v2 = Wm[(size_t)(d0 + 2) * HFsz + c];
    const float v3 = Wm[(size_t)(d0 + 3) * HFsz + c];
    uint2 pk;
    pk.x = f2bf(v0) | (f2bf(v1) << 16);
    pk.y = f2bf(v2) | (f2bf(v3) << 16);
    *(uint2*)&WbT[(size_t)c * Dsz + d0] = pk;   // coalesced 512B/wave
}

// ---------------------------------------------------------------------------
// Kernel 0.5: adj -> bitmask, tile-major layout.
// adjM byte address: (r>>4)*2048 + (j8>>3)*128 + (r&15)*8 + (j8&7)
//   where r = b*1024+i, j8 = j>>3, bit w of byte = (adj[r][j8*8+w] > 0.5).
// => tile (it,jt): row m's u64 mask at (b*64+it)*2048 + jt*128 + m*8;
//    bit k of that u64 = column jt*64+k. (unchanged, verified)
// ---------------------------------------------------------------------------
__global__ __launch_bounds__(256) void adjbin(const float* __restrict__ adj,
                                              unsigned char* __restrict__ adjM) {
    const int wg = (blockIdx.x * 256 + threadIdx.x) >> 6;   // wave id [0,2048)
    const int lane = threadIdx.x & 63;
#pragma unroll 1
    for (int s = wg; s < 32768; s += 2048) {                // 2 spans x 16384 rows
        const int r = s >> 1, c0 = (s & 1) * 512;
        const float4* src = (const float4*)(adj + (size_t)r * 1024 + c0 + lane * 8);
        const float4 a0 = src[0], a1 = src[1];              // 2 KB/wave, coalesced
        unsigned by = 0;
        by |= (a0.x > 0.5f) ? 1u : 0u;
        by |= (a0.y > 0.5f) ? 2u : 0u;
        by |= (a0.z > 0.5f) ? 4u : 0u;
        by |= (a0.w > 0.5f) ? 8u : 0u;
        by |= (a1.x > 0.5f) ? 16u : 0u;
        by |= (a1.y > 0.5f) ? 32u : 0u;
        by |= (a1.z > 0.5f) ? 64u : 0u;
        by |= (a1.w > 0.5f) ? 128u : 0u;
        const int j8 = (s & 1) * 64 + lane;
        adjM[(size_t)(r >> 4) * 2048 + (j8 >> 3) * 128 + (r & 15) * 8 + (j8 & 7)] =
            (unsigned char)by;
    }
}

// ---------------------------------------------------------------------------
// Kernel 1: hT = bf16(x @ W)^T via MFMA + fused e_src/e_dst (fp32 dots).
// e_src/e_dst stored PRE-SCALED by log2(e). (unchanged, verified)
// ---------------------------------------------------------------------------
__global__ __launch_bounds__(256) void gat_h_e3(
    const float* __restrict__ x,              // [BN][D]
    const unsigned short* __restrict__ WbT,   // [HF][D] bf16
    const float* __restrict__ a_src,          // [HF]
    const float* __restrict__ a_dst,          // [HF]
    unsigned short* __restrict__ hT,          // [B][HF][N] bf16
    float* __restrict__ esrcT,                // [B][H][N]  (x log2e)
    float* __restrict__ edstT)                // [B][H][N]  (x log2e)
{
    const int n0g = blockIdx.x * 32, b = n0g >> 10, n0 = n0g & 1023;
    const int t = threadIdx.x, lane = t & 63, w = t >> 6;
    const int m = lane & 15, q = lane >> 4;

    __shared__ alignas(16) unsigned short Lds[4 * 64 * 40];  // 10240 hw = 20 KB

    const float4* x4 = (const float4*)(x + (size_t)n0g * Dsz);
#pragma unroll
    for (int i = 0; i < 8; ++i) {
        const int f = t + 256 * i;
        const int row = f >> 6, d4 = (f & 63) * 4;
        const float4 xv = x4[f];
        uint2 pk;
        pk.x = f2bf(xv.x) | (f2bf(xv.y) << 16);
        pk.y = f2bf(xv.z) | (f2bf(xv.w) << 16);
        *(uint2*)&Lds[row * 264 + d4] = pk;
    }
    __syncthreads();

    const unsigned short* Ab = WbT + (size_t)(w * 64 + m) * Dsz + q * 8;
    f32x4 acc[4][2];
#pragma unroll
    for (int ht = 0; ht < 4; ++ht)
#pragma unroll
        for (int nt = 0; nt < 2; ++nt) acc[ht][nt] = (f32x4){0.f, 0.f, 0.f, 0.f};

#pragma unroll
    for (int kk = 0; kk < 8; ++kk) {
        const int k0 = kk * 32;
        const bf16x8 bfr0 = *(const bf16x8*)&Lds[(0 * 16 + m) * 264 + k0 + q * 8];
        const bf16x8 bfr1 = *(const bf16x8*)&Lds[(1 * 16 + m) * 264 + k0 + q * 8];
#pragma unroll
        for (int ht = 0; ht < 4; ++ht) {
            const bf16x8 afr = *(const bf16x8*)&Ab[ht * 16 * Dsz + k0];
            acc[ht][0] = __builtin_amdgcn_mfma_f32_16x16x32_bf16(afr, bfr0, acc[ht][0], 0, 0, 0);
            acc[ht][1] = __builtin_amdgcn_mfma_f32_16x16x32_bf16(afr, bfr1, acc[ht][1], 0, 0, 0);
        }
    }

    float ps0 = 0.f, ps1 = 0.f, pd0 = 0.f, pd1 = 0.f;
#pragma unroll
    for (int ht = 0; ht < 4; ++ht)
#pragma unroll
        for (int r = 0; r < 4; ++r) {
            const float as = a_src[w * 64 + ht * 16 + q * 4 + r];
            const float ad = a_dst[w * 64 + ht * 16 + q * 4 + r];
            ps0 += acc[ht][0][r] * as;  ps1 += acc[ht][1][r] * as;
            pd0 += acc[ht][0][r] * ad;  pd1 += acc[ht][1][r] * ad;
        }
    ps0 += __shfl_xor(ps0, 16, 64); ps0 += __shfl_xor(ps0, 32, 64);
    ps1 += __shfl_xor(ps1, 16, 64); ps1 += __shfl_xor(ps1, 32, 64);
    pd0 += __shfl_xor(pd0, 16, 64); pd0 += __shfl_xor(pd0, 32, 64);
    pd1 += __shfl_xor(pd1, 16, 64); pd1 += __shfl_xor(pd1, 32, 64);
    if (q == 0) {
        const size_t eb = (size_t)(b * Hsz + w) * Nsz + n0;
        esrcT[eb + m]      = ps0 * LOG2E;  esrcT[eb + 16 + m] = ps1 * LOG2E;
        edstT[eb + m]      = pd0 * LOG2E;  edstT[eb + 16 + m] = pd1 * LOG2E;
    }

    __syncthreads();   // xs no longer needed; reuse LDS as hs[4][64][40]

#pragma unroll
    for (int ht = 0; ht < 4; ++ht)
#pragma unroll
        for (int r = 0; r < 4; ++r) {
            const int hf = ht * 16 + q * 4 + r;
            Lds[w * 2560 + hf * 40 + m]      = (unsigned short)f2bf(acc[ht][0][r]);
            Lds[w * 2560 + hf * 40 + 16 + m] = (unsigned short)f2bf(acc[ht][1][r]);
        }
#pragma unroll
    for (int s = 0; s < 4; ++s) {
        const int hf = s * 16 + (lane >> 2), ck = lane & 3;
        const bf16x8 hv = *(const bf16x8*)&Lds[w * 2560 + hf * 40 + ck * 8];
        *(bf16x8*)&hT[(size_t)(b * HFsz + w * 64 + hf) * Nsz + n0 + ck * 8] = hv;
    }
}

// ---------------------------------------------------------------------------
// Kernel 2 (v11): v8 minus the LDS P round-trip -- fragment-direct P in VGPRs.
// R11 post-mortem: v10's reg-pipeline collapsed occupancy (35%) and the
// compiler refused the double-buffer anyway (VGPR 52). Revert to v8 (67us)
// and remove its one remaining in-wave serializer: the P LDS hop
// (16 ds_write -> lgkmcnt drain -> 2 ds_read, ~200cy serial + 786K bank
// conflicts). Each lane (m,q) now computes its A-frag elements
// P[m][j0+kk*32+q*8+r] directly: mask = bit (q*8+r) of dword kk of row m's
// u64 (one per-lane dwordx2 from adjM, addresses 16-way-broadcast within
// 128 B); es = two L1-resident float4 per kk; ed = edb[m] per lane.
// P: exp -> af VGPRs -> MFMA, never touches memory. ~3 extra VALU/element
// for bit tests, minus 18 LDS instrs + drain per tile. Load schedule, ones
// denominator, acc layout, epilogue, (128,6): byte-identical to v8.
// ---------------------------------------------------------------------------
__global__ __launch_bounds__(128, 6) void gat_attn11(
    const unsigned char* __restrict__ adjM, // [B][64][16][128B] bit-tiles
    const unsigned short* __restrict__ hT,  // [B][HF][N] bf16
    const float* __restrict__ esrcT,        // [B][H][N] (x log2e)
    const float* __restrict__ edstT,        // [B][H][N] (x log2e)
    const float* __restrict__ bias,         // [HF]
    float* __restrict__ outp)               // [BN][HF]
{
    const int gid = blockIdx.x;
    const int b  = gid & 15;                 // xcd = gid%8 -> b%8 (L2 locality)
    const int hw = (gid >> 4) & 3;           // head
    const int it = gid >> 6, i0 = it * 16;
    const int t = threadIdx.x;
    const int lane = t & 63, jh = t >> 6;    // jh = j-half (2 waves)
    const int m = lane & 15, q = lane >> 4;

    __shared__ alignas(16) float smem[2560]; // epilogue comb[2][64][20] only

    const float* esb = esrcT + (size_t)(b * Hsz + hw) * Nsz;
    const float ed_s = edstT[(size_t)(b * Hsz + hw) * Nsz + i0 + m];  // row m
    const unsigned short* hTb = hT + (size_t)(b * HFsz + hw * 64 + m) * Nsz + q * 8;
    const unsigned char* mkb = adjM + (size_t)(b * 64 + it) * 2048 + m * 8;

    bf16x8 ones;                             // denominator row-sum B-frag
#pragma unroll
    for (int i = 0; i < 8; ++i)
        ((unsigned short*)&ones)[i] = 0x3F80;   // bf16 1.0

    f32x4 acc[4];
#pragma unroll
    for (int nt = 0; nt < 4; ++nt) acc[nt] = (f32x4){0.f, 0.f, 0.f, 0.f};
    f32x4 acc5 = (f32x4){0.f, 0.f, 0.f, 0.f};

    const int jt0 = jh * 8;                  // this wave's 8 j-tiles
    const int q8 = q * 8;

#pragma unroll 1
    for (int jl = 0; jl < 8; ++jl) {
        const int jt = jt0 + jl;
        const int j0 = jt * 64;

        // (a) per-lane row-mask u64 (16 distinct addrs in 128 B -> L2/L1 hot)
        const unsigned long long mk =
            *(const unsigned long long*)(mkb + jt * 128);
        // (b) kk=0 hT loads (consumed after exp chain kk0)
        bf16x8 bfr0[4], bfr1[4];
#pragma unroll
        for (int nt = 0; nt < 4; ++nt)
            bfr0[nt] = *(const bf16x8*)&hTb[(size_t)nt * 16 * Nsz + j0];
        // (c) es for kk0 frag: 8 consecutive floats (L1-broadcast over m)
        const float4 e0a = *(const float4*)&esb[j0 + q8];
        const float4 e0b = *(const float4*)&esb[j0 + q8 + 4];

        const unsigned mlo = (unsigned)mk, mhi = (unsigned)(mk >> 32);
        const unsigned by0 = mlo >> q8;      // bits 0..7 = frag elements kk0

        // (d) exp chain kk0 -> af0 (pure registers)
        union { unsigned u[4]; bf16x8 v; } af0;
        {
            const float e[8] = {e0a.x, e0a.y, e0a.z, e0a.w,
                                e0b.x, e0b.y, e0b.z, e0b.w};
#pragma unroll
            for (int r = 0; r < 4; ++r) {
                float va = ed_s + e[2 * r], vb = ed_s + e[2 * r + 1];
                va = fmaxf(va, 0.2f * va);   // LeakyReLU (scale>0 commutes)
                vb = fmaxf(vb, 0.2f * vb);
                float pa, pb;
                asm("v_exp_f32 %0, %1" : "=v"(pa) : "v"(va));   // 2^v
                asm("v_exp_f32 %0, %1" : "=v"(pb) : "v"(vb));
                const unsigned ua = ((by0 >> (2 * r)) & 1u) ? __float_as_uint(pa) : 0u;
                const unsigned ub = ((by0 >> (2 * r + 1)) & 1u) ? __float_as_uint(pb) : 0u;
                af0.u[r] = (ua >> 16) | (ub & 0xFFFF0000u);     // 2x bf16 trunc
            }
        }

        // (e) kk=1 hT + es loads (land under kk0 MFMAs)
#pragma unroll
        for (int nt = 0; nt < 4; ++nt)
            bfr1[nt] = *(const bf16x8*)&hTb[(size_t)nt * 16 * Nsz + j0 + 32];
        const float4 e1a = *(const float4*)&esb[j0 + 32 + q8];
        const float4 e1b = *(const float4*)&esb[j0 + 32 + q8 + 4];

        // (f) kk0 MFMAs
#pragma unroll
        for (int nt = 0; nt < 4; ++nt)
            acc[nt] = __builtin_amdgcn_mfma_f32_16x16x32_bf16(
                af0.v, bfr0[nt], acc[nt], 0, 0, 0);
        acc5 = __builtin_amdgcn_mfma_f32_16x16x32_bf16(af0.v, ones, acc5, 0, 0, 0);

        // (g) exp chain kk1 -> af1
        union { unsigned u[4]; bf16x8 v; } af1;
        {
            const unsigned by1 = mhi >> q8;
            const float e[8] = {e1a.x, e1a.y, e1a.z, e1a.w,
                                e1b.x, e1b.y, e1b.z, e1b.w};
#pragma unroll
            for (int r = 0; r < 4; ++r) {
                float va = ed_s + e[2 * r], vb = ed_s + e[2 * r + 1];
                va = fmaxf(va, 0.2f * va);
                vb = fmaxf(vb, 0.2f * vb);
                float pa, pb;
                asm("v_exp_f32 %0, %1" : "=v"(pa) : "v"(va));
                asm("v_exp_f32 %0, %1" : "=v"(pb) : "v"(vb));
                const unsigned ua = ((by1 >> (2 * r)) & 1u) ? __float_as_uint(pa) : 0u;
                const unsigned ub = ((by1 >> (2 * r + 1)) & 1u) ? __float_as_uint(pb) : 0u;
                af1.u[r] = (ua >> 16) | (ub & 0xFFFF0000u);
            }
        }

        // (h) kk1 MFMAs
#pragma unroll
        for (int nt = 0; nt < 4; ++nt)
            acc[nt] = __builtin_amdgcn_mfma_f32_16x16x32_bf16(
                af1.v, bfr1[nt], acc[nt], 0, 0, 0);
        acc5 = __builtin_amdgcn_mfma_f32_16x16x32_bf16(af1.v, ones, acc5, 0, 0, 0);
    }

    // ---- combine the 2 j-half partials (verified v8 epilogue, unchanged) ----
    __syncthreads();
    {
        float* cw = smem + t * 20;           // (jh*64+lane)*20 == t*20
#pragma unroll
        for (int nt = 0; nt < 4; ++nt)
#pragma unroll
            for (int r = 0; r < 4; ++r) cw[nt * 4 + r] = acc[nt][r];
#pragma unroll
        for (int r = 0; r < 4; ++r) cw[16 + r] = acc5[r];   // den rows q*4+r
    }
    __syncthreads();

#pragma unroll
    for (int u = 0; u < 2; ++u) {
        const int idx = t * 2 + u;               // 256 float4 cells (16x16)
        const int row = idx >> 4, c4 = idx & 15;
        const int rq = row >> 2, rr = row & 3;
        const int nt4 = (c4 >> 2) * 4, mb = (c4 & 3) * 4;
        float n0 = 0.f, n1 = 0.f, n2 = 0.f, n3 = 0.f, den = 0.f;
#pragma unroll
        for (int j2 = 0; j2 < 2; ++j2) {
            const float* cb = smem + (j2 * 64 + rq * 16) * 20;
            den += cb[16 + rr];                  // m=0 copy
            n0 += cb[(mb + 0) * 20 + nt4 + rr];
            n1 += cb[(mb + 1) * 20 + nt4 + rr];
            n2 += cb[(mb + 2) * 20 + nt4 + rr];
            n3 += cb[(mb + 3) * 20 + nt4 + rr];
        }
        const float inv = 1.f / den;
        const float4 b4 = *(const float4*)&bias[hw * 64 + c4 * 4];
        float4 o;
        o.x = n0 * inv + b4.x;  o.y = n1 * inv + b4.y;
        o.z = n2 * inv + b4.z;  o.w = n3 * inv + b4.w;
        *(float4*)&outp[(size_t)(b * Nsz + i0 + row) * HFsz + hw * 64 + c4 * 4] = o;
    }
}

// ---------------------------------------------------------------------------
extern "C" void kernel_launch(void* const* d_in, const int* in_sizes, int n_in,
                              void* d_out, int out_size, void* d_ws, size_t ws_size,
                              hipStream_t stream) {
    const float* x     = (const float*)d_in[0];
    const float* adj   = (const float*)d_in[1];
    const float* Wm    = (const float*)d_in[2];
    const float* a_src = (const float*)d_in[3];
    const float* a_dst = (const float*)d_in[4];
    const float* bias  = (const float*)d_in[5];
    float* outp = (float*)d_out;

    // ws: hT bf16 (8MB) | WbT bf16 (128KB) | esrcT (256KB) | edstT (256KB) | adjM (2MB)
    unsigned short* hT  = (unsigned short*)d_ws;
    unsigned short* WbT = hT + (size_t)BN * HFsz;
    float* esrcT = (float*)(WbT + (size_t)HFsz * Dsz);
    float* edstT = esrcT + (size_t)Bsz * Hsz * Nsz;
    unsigned char* adjM = (unsigned char*)(edstT + (size_t)Bsz * Hsz * Nsz);

    adjbin<<<dim3(512), dim3(256), 0, stream>>>(adj, adjM);
    wcvt<<<dim3(64), dim3(256), 0, stream>>>(Wm, WbT);
    gat_h_e3<<<dim3(BN / 32), dim3(256), 0, stream>>>(x, WbT, a_src, a_dst,
                                                      hT, esrcT, edstT);
    gat_attn11<<<dim3(4096), dim3(128), 0, stream>>>(adjM, hT, esrcT, edstT,
                                                     bias, outp);
}